// Round 3
// 2959.450 us; speedup vs baseline: 1.2594x; 1.2594x over previous
//
#include <hip/hip_runtime.h>
#include <stdint.h>

// ---------- types / helpers ----------
typedef __attribute__((ext_vector_type(8))) short short8;   // 8 bf16 in 4 VGPRs
typedef __attribute__((ext_vector_type(4))) float f32x4;

__device__ __forceinline__ unsigned short f32_to_bf16(float f) {
    unsigned int u = __float_as_uint(f);
    unsigned int r = (u + 0x7FFF + ((u >> 16) & 1)) >> 16;   // RNE
    return (unsigned short)r;
}
__device__ __forceinline__ float bf16_to_f32(unsigned short s) {
    return __uint_as_float(((unsigned int)s) << 16);
}

__device__ __forceinline__ float sigm_fast(float z) {
    return __fdividef(1.f, 1.f + __expf(-z));
}
__device__ __forceinline__ float tanh_fast(float z) {
    float a = fabsf(z);
    float e = __expf(-2.f * a);                 // in (0,1], no overflow
    float r = __fdividef(1.f - e, 1.f + e);
    return copysignf(r, z);
}

// ---------- prep kernels ----------
__global__ void cvt_bf16_kernel(const float* __restrict__ in,
                                unsigned short* __restrict__ out, int n) {
    int i = (blockIdx.x * blockDim.x + threadIdx.x) * 4;
    if (i >= n) return;
    float4 v = *(const float4*)(in + i);
    ushort4 o;
    o.x = f32_to_bf16(v.x);
    o.y = f32_to_bf16(v.y);
    o.z = f32_to_bf16(v.z);
    o.w = f32_to_bf16(v.w);
    *(ushort4*)(out + i) = o;
}

__global__ void bias_add_kernel(const float* __restrict__ bi,
                                const float* __restrict__ bh,
                                float* __restrict__ bias) {
    int i = blockIdx.x * blockDim.x + threadIdx.x;  // 4096
    bias[i] = bi[i] + bh[i];
}

__global__ void zero_kernel(unsigned int* __restrict__ p, int n) {
    int i = blockIdx.x * blockDim.x + threadIdx.x;
    if (i < n) p[i] = 0u;
}

// h0 [b][j] fp32 -> hG0 in B-fragment order:
// dword D = ((kq)*32 + b)*4 + i2, holding bf16 h[j = kq*8 + i2*2], h[j+1] for batch b.
__global__ void hG_init_kernel(const float* __restrict__ h0,
                               unsigned int* __restrict__ hG) {
    int D = blockIdx.x * blockDim.x + threadIdx.x;  // 16384
    int i2 = D & 3, b = (D >> 2) & 31, kq = D >> 7;
    int j = kq * 8 + i2 * 2;
    unsigned int lo = f32_to_bf16(h0[b * 1024 + j]);
    unsigned int hi = f32_to_bf16(h0[b * 1024 + j + 1]);
    hG[D] = lo | (hi << 16);
}

// ---------- phase 1: xg[r][g] = bf16( x[r][:]·W_ih[g][:] + bias[g] ), r=b*512+t ----------
#define LDP 40  // padded LDS row pitch (shorts): 2-way conflicts only (free)

__global__ __launch_bounds__(256) void gemm_xproj(
    const unsigned short* __restrict__ A,   // x bf16 [16384][1024]
    const unsigned short* __restrict__ B,   // W_ih bf16 [4096][1024]
    const float* __restrict__ bias,         // [4096]
    unsigned short* __restrict__ C) {       // xg bf16 [16384][4096]
    __shared__ unsigned short As[64][LDP];
    __shared__ unsigned short Bs[64][LDP];
    const int tid  = threadIdx.x;
    const int lane = tid & 63;
    const int wave = tid >> 6;
    const int m0 = blockIdx.y * 64;
    const int n0 = blockIdx.x * 64;
    const int wm = (wave & 1) * 32;
    const int wn = (wave >> 1) * 32;

    f32x4 acc[2][2] = {};

    const int sr = tid >> 2;
    const int sk = (tid & 3) * 8;
    const int fr = lane & 15;
    const int fk = (lane >> 4) * 8;

    for (int k0 = 0; k0 < 1024; k0 += 32) {
        uint4 av = *(const uint4*)&A[(m0 + sr) * 1024 + k0 + sk];
        uint4 bv = *(const uint4*)&B[(n0 + sr) * 1024 + k0 + sk];
        __syncthreads();
        *(uint4*)&As[sr][sk] = av;
        *(uint4*)&Bs[sr][sk] = bv;
        __syncthreads();
        short8 a0 = *(const short8*)&As[wm + fr][fk];
        short8 a1 = *(const short8*)&As[wm + 16 + fr][fk];
        short8 b0 = *(const short8*)&Bs[wn + fr][fk];
        short8 b1 = *(const short8*)&Bs[wn + 16 + fr][fk];
        acc[0][0] = __builtin_amdgcn_mfma_f32_16x16x32_bf16(a0, b0, acc[0][0], 0, 0, 0);
        acc[0][1] = __builtin_amdgcn_mfma_f32_16x16x32_bf16(a0, b1, acc[0][1], 0, 0, 0);
        acc[1][0] = __builtin_amdgcn_mfma_f32_16x16x32_bf16(a1, b0, acc[1][0], 0, 0, 0);
        acc[1][1] = __builtin_amdgcn_mfma_f32_16x16x32_bf16(a1, b1, acc[1][1], 0, 0, 0);
    }

    const int col = lane & 15;
    const int rq  = (lane >> 4) * 4;
    for (int mt = 0; mt < 2; mt++) {
        for (int nt = 0; nt < 2; nt++) {
            int gcol = n0 + wn + nt * 16 + col;
            float bv = bias[gcol];
            for (int r = 0; r < 4; r++) {
                int grow = m0 + wm + mt * 16 + rq + r;
                C[(size_t)grow * 4096 + gcol] = f32_to_bf16(acc[mt][nt][r] + bv);
            }
        }
    }
}

// ---------- phase 2: persistent recurrence, 64 blocks x 512 threads ----------
// Block bid owns hidden units j0=16*bid..+15 (64 gate rows = 4 gates x 16 units).
// W_hh slice lives ENTIRELY in VGPRs: af[gate][u] = 128 VGPRs/lane (A-fragment order).
// Wave (ks,nt): K-chunk ks*256, batch half nt -> duplication-free h reads:
// block reads h once (64 KB), grid total 4 MB/step (was 16 MB with 256 blocks).
// Exchange: partial[ks][gate][batch][unit] fp32 (32 KB LDS, b128 writes, 2-way reads).
// Epilogue: all 512 threads, one (batch,unit) each; c persists in a VGPR.
// Barrier: 64 flags, published by tid==0 after a drained sc1 h-store; polled by
// wave 0 only (one lane per flag, __all ballot). Raw sc0/sc1 ops only — no
// compiler atomics (their cache-maintenance storm was a prior regression).
// NOTE 1 (hipcc/gfx950 asm quirk): uint4 works as "=v" OUTPUT (loads) but NOT as
// "v" INPUT (stores) -> publish uses 2x dwordx2 with uint2.
// NOTE 2 (rule #18): MFMA here is register-only (af in VGPRs, no ds_read), so the
// compiler CAN hoist it past the separate `s_waitcnt vmcnt(0)` asm despite the
// memory clobber -> it would read in-flight load dests (NaN). The fence is
// __builtin_amdgcn_sched_barrier(0) immediately after the drain.
__global__ __launch_bounds__(512, 2) void lstm_persist(
    const float* __restrict__ Whh,          // [4096][1024] fp32
    const unsigned short* __restrict__ xg,  // bf16 [16384][4096], bias folded
    const float* __restrict__ c0,           // [32][1024] fp32
    unsigned int* __restrict__ hG0,         // 16384 dwords, frag-order h (t even reads)
    unsigned int* __restrict__ hG1,
    unsigned int* __restrict__ flags,       // [512][64]
    float* __restrict__ out) {              // [32][1024] fp32
    __shared__ float partial[4][4][32][16];     // 32 KB [ks][gate][batch][unit]
    __shared__ unsigned short hout[32][16];     // 1 KB  [batch][unit]

    const int tid  = threadIdx.x;
    const int bid  = blockIdx.x;
    const int j0   = bid * 16;
    const int lane = tid & 63;
    const int wave = tid >> 6;
    const int ks   = wave >> 1;   // K-split 0..3 (256 k each)
    const int nt   = wave & 1;    // batch half (0-15 / 16-31)
    const int col  = lane & 15;
    const int quad = lane >> 4;

    // ---- stage W_hh slice -> A-fragments in VGPRs (once) ----
    // af[mt][u]: lane holds A[row = mt*16 + col][k-octet = (ks*8+u)*4 + quad].
    short8 af[4][8];
#pragma unroll
    for (int mt = 0; mt < 4; ++mt) {
#pragma unroll
        for (int u = 0; u < 8; ++u) {
            const float* wr = Whh + (size_t)(mt * 1024 + j0 + col) * 1024
                              + (ks * 8 + u) * 32 + quad * 8;
            float4 wa = *(const float4*)wr;
            float4 wb = *(const float4*)(wr + 4);
            short8 v;
            v[0] = (short)f32_to_bf16(wa.x); v[1] = (short)f32_to_bf16(wa.y);
            v[2] = (short)f32_to_bf16(wa.z); v[3] = (short)f32_to_bf16(wa.w);
            v[4] = (short)f32_to_bf16(wb.x); v[5] = (short)f32_to_bf16(wb.y);
            v[6] = (short)f32_to_bf16(wb.z); v[7] = (short)f32_to_bf16(wb.w);
            af[mt][u] = v;
        }
        asm volatile("" ::: "memory");  // cap transient staging register pressure
    }

    const int eb = tid >> 4;     // epilogue batch 0..31
    const int ej = tid & 15;     // epilogue unit  0..15
    float cst = c0[eb * 1024 + j0 + ej];

    const int kq0  = bid * 2;          // this block's two h k-octets
    const int bofs = nt * 16 + col;    // wave's batch index for B-frag / partial

    __syncthreads();

    for (int t = 0; t < 512; ++t) {
        const unsigned int* hR = (t & 1) ? hG1 : hG0;
        unsigned int*       hW = (t & 1) ? hG0 : hG1;

        // prefetch xg gate inputs (independent of h)
        const unsigned short* px = xg + (size_t)(eb * 512 + t) * 4096 + j0 + ej;
        unsigned short x0 = px[0];
        unsigned short x1 = px[1024];
        unsigned short x2 = px[2048];
        unsigned short x3 = px[3072];

        // B-fragments: LLC-coherent loads (h(t) published before prev barrier)
        uint4 bv[8];
#pragma unroll
        for (int u = 0; u < 8; ++u) {
            int kc = ks * 8 + u;
            const unsigned int* p = hR + ((kc * 4 + quad) * 32 + bofs) * 4;
            asm volatile("global_load_dwordx4 %0, %1, off sc1"
                         : "=v"(bv[u]) : "v"(p) : "memory");
        }
        asm volatile("s_waitcnt vmcnt(0)" ::: "memory");
        __builtin_amdgcn_sched_barrier(0);   // rule #18: pin MFMA below the drain

        f32x4 acc[4] = {};
#pragma unroll
        for (int u = 0; u < 8; ++u) {
            union { uint4 u4; short8 s8; } cv;
            cv.u4 = bv[u];
#pragma unroll
            for (int mt = 0; mt < 4; ++mt)
                acc[mt] = __builtin_amdgcn_mfma_f32_16x16x32_bf16(af[mt][u], cv.s8,
                                                                  acc[mt], 0, 0, 0);
        }
        // write partials: C row (quad*4+r) = unit, C col = batch-local
#pragma unroll
        for (int mt = 0; mt < 4; ++mt)
            *(f32x4*)&partial[ks][mt][bofs][quad * 4] = acc[mt];
        __syncthreads();

        // epilogue: every thread owns one (batch, unit)
        float z[4];
#pragma unroll
        for (int q = 0; q < 4; ++q)
            z[q] = partial[0][q][eb][ej] + partial[1][q][eb][ej] +
                   partial[2][q][eb][ej] + partial[3][q][eb][ej];
        z[0] += bf16_to_f32(x0);
        z[1] += bf16_to_f32(x1);
        z[2] += bf16_to_f32(x2);
        z[3] += bf16_to_f32(x3);
        float ig = sigm_fast(z[0]);
        float fg = sigm_fast(z[1]);
        float gg = tanh_fast(z[2]);
        float og = sigm_fast(z[3]);
        cst = fg * cst + ig * gg;
        float hn = og * tanh_fast(cst);
        hout[eb][ej] = f32_to_bf16(hn);
        if (t == 511) {                       // uniform: final output, no publish
            out[eb * 1024 + j0 + ej] = hn;
            break;
        }
        __syncthreads();                      // hout ready for publishers

        // publish this block's 16 h values per batch (LLC write-through),
        // drain vmcnt BEFORE the flag store issues -> h visible before flag.
        if (tid < 64) {
            int bb = tid & 31, kl = tid >> 5;
            uint2 d0 = *(const uint2*)&hout[bb][kl * 8];
            uint2 d1 = *(const uint2*)&hout[bb][kl * 8 + 4];
            unsigned int* p = hW + ((kq0 + kl) * 32 + bb) * 4;
            asm volatile("global_store_dwordx2 %0, %1, off sc1"
                         :: "v"(p), "v"(d0) : "memory");
            asm volatile("global_store_dwordx2 %0, %1, off sc1\n\ts_waitcnt vmcnt(0)"
                         :: "v"(p + 2), "v"(d1) : "memory");
        }
        // barrier arrive: plain LLC store of 1 (same wave as publish -> ordered)
        if (tid == 0) {
            unsigned int one = 1u;
            asm volatile("global_store_dword %0, %1, off sc0 sc1"
                         :: "v"(flags + t * 64 + bid), "v"(one) : "memory");
        }
        // barrier wait: ONE wave polls, one flag per lane, ballot exit
        if (wave == 0) {
            const unsigned int* fp = flags + t * 64 + lane;
            unsigned int v;
            for (;;) {
                asm volatile("global_load_dword %0, %1, off sc0 sc1\n\ts_waitcnt vmcnt(0)"
                             : "=v"(v) : "v"(fp) : "memory");
                if (__all(v != 0u)) break;
                __builtin_amdgcn_s_sleep(1);
            }
        }
        __syncthreads();
    }
}

// ---------- launch ----------
extern "C" void kernel_launch(void* const* d_in, const int* in_sizes, int n_in,
                              void* d_out, int out_size, void* d_ws, size_t ws_size,
                              hipStream_t stream) {
    const float* x    = (const float*)d_in[0];  // [32][512][1024]
    const float* h0   = (const float*)d_in[1];  // [32][1024]
    const float* c0   = (const float*)d_in[2];  // [32][1024]
    const float* Wih  = (const float*)d_in[3];  // [4096][1024]
    const float* Whh  = (const float*)d_in[4];  // [4096][1024]
    const float* b_ih = (const float*)d_in[5];  // [4096]
    const float* b_hh = (const float*)d_in[6];  // [4096]
    float* out = (float*)d_out;
    char* ws = (char*)d_ws;

    // workspace layout (fits in the round-2-proven 176,439,296 B):
    //   xg    @ 0          134217728 B (bf16, live through persistent phase)
    //   xA    @ 134217728   33554432 B (bf16 x; DEAD after gemm -> flags overlay)
    //   wB    @ 167772160    8388608 B (bf16 W_ih)
    //   bias  @ 176160768      16384 B
    //   hG0   @ 176177152      65536 B
    //   hG1   @ 176242688      65536 B  (end 176308224)
    unsigned short* xg   = (unsigned short*)(ws);
    unsigned short* xA   = (unsigned short*)(ws + 134217728);
    unsigned short* wB   = (unsigned short*)(ws + 167772160);
    float*          bias = (float*)(ws + 176160768);
    unsigned int*   hG0  = (unsigned int*)(ws + 176177152);
    unsigned int*   hG1  = (unsigned int*)(ws + 176242688);
    unsigned int*   flags = (unsigned int*)(ws + 134217728);  // overlays xA after gemm

    cvt_bf16_kernel<<<16384, 256, 0, stream>>>(x, xA, 16777216);
    cvt_bf16_kernel<<<4096, 256, 0, stream>>>(Wih, wB, 4194304);
    bias_add_kernel<<<16, 256, 0, stream>>>(b_ih, b_hh, bias);

    dim3 g1(64, 256);
    gemm_xproj<<<g1, 256, 0, stream>>>(xA, wB, bias, xg);

    // xA dead from here; reuse as flag storage (512 steps x 64 blocks)
    zero_kernel<<<128, 256, 0, stream>>>(flags, 512 * 64);
    hG_init_kernel<<<64, 256, 0, stream>>>(h0, hG0);

    lstm_persist<<<64, 512, 0, stream>>>(Whh, xg, c0, hG0, hG1, flags, out);
}

// Round 4
// 2052.404 us; speedup vs baseline: 1.8160x; 1.4419x over previous
//
#include <hip/hip_runtime.h>
#include <stdint.h>

// ---------- types / helpers ----------
typedef __attribute__((ext_vector_type(8))) short short8;   // 8 bf16 in 4 VGPRs
typedef __attribute__((ext_vector_type(4))) float f32x4;

__device__ __forceinline__ unsigned short f32_to_bf16(float f) {
    unsigned int u = __float_as_uint(f);
    unsigned int r = (u + 0x7FFF + ((u >> 16) & 1)) >> 16;   // RNE
    return (unsigned short)r;
}
__device__ __forceinline__ float bf16_to_f32(unsigned short s) {
    return __uint_as_float(((unsigned int)s) << 16);
}

__device__ __forceinline__ float sigm_fast(float z) {
    return __fdividef(1.f, 1.f + __expf(-z));
}
__device__ __forceinline__ float tanh_fast(float z) {
    float a = fabsf(z);
    float e = __expf(-2.f * a);                 // in (0,1], no overflow
    float r = __fdividef(1.f - e, 1.f + e);
    return copysignf(r, z);
}

// ---------- prep kernels ----------
__global__ void cvt_bf16_kernel(const float* __restrict__ in,
                                unsigned short* __restrict__ out, int n) {
    int i = (blockIdx.x * blockDim.x + threadIdx.x) * 4;
    if (i >= n) return;
    float4 v = *(const float4*)(in + i);
    ushort4 o;
    o.x = f32_to_bf16(v.x);
    o.y = f32_to_bf16(v.y);
    o.z = f32_to_bf16(v.z);
    o.w = f32_to_bf16(v.w);
    *(ushort4*)(out + i) = o;
}

__global__ void bias_add_kernel(const float* __restrict__ bi,
                                const float* __restrict__ bh,
                                float* __restrict__ bias) {
    int i = blockIdx.x * blockDim.x + threadIdx.x;  // 4096
    bias[i] = bi[i] + bh[i];
}

__global__ void fill_kernel(unsigned int* __restrict__ p, unsigned int v, int n) {
    int i = blockIdx.x * blockDim.x + threadIdx.x;
    if (i < n) p[i] = v;
}

// h0 [b][j] fp32 -> slot 0 of hSeq in B-fragment order:
// dword D = ((kq)*32 + b)*4 + i2, holding bf16 h[j = kq*8 + i2*2], h[j+1] for batch b.
__global__ void hG_init_kernel(const float* __restrict__ h0,
                               unsigned int* __restrict__ hG) {
    int D = blockIdx.x * blockDim.x + threadIdx.x;  // 16384
    int i2 = D & 3, b = (D >> 2) & 31, kq = D >> 7;
    int j = kq * 8 + i2 * 2;
    unsigned int lo = f32_to_bf16(h0[b * 1024 + j]);
    unsigned int hi = f32_to_bf16(h0[b * 1024 + j + 1]);
    hG[D] = lo | (hi << 16);
}

// ---------- phase 1: xg[r][g] = bf16( x[r][:]·W_ih[g][:] + bias[g] ), r=b*512+t ----------
#define LDP 40  // padded LDS row pitch (shorts): 2-way conflicts only (free)

__global__ __launch_bounds__(256) void gemm_xproj(
    const unsigned short* __restrict__ A,   // x bf16 [16384][1024]
    const unsigned short* __restrict__ B,   // W_ih bf16 [4096][1024]
    const float* __restrict__ bias,         // [4096]
    unsigned short* __restrict__ C) {       // xg bf16 [16384][4096]
    __shared__ unsigned short As[64][LDP];
    __shared__ unsigned short Bs[64][LDP];
    const int tid  = threadIdx.x;
    const int lane = tid & 63;
    const int wave = tid >> 6;
    const int m0 = blockIdx.y * 64;
    const int n0 = blockIdx.x * 64;
    const int wm = (wave & 1) * 32;
    const int wn = (wave >> 1) * 32;

    f32x4 acc[2][2] = {};

    const int sr = tid >> 2;
    const int sk = (tid & 3) * 8;
    const int fr = lane & 15;
    const int fk = (lane >> 4) * 8;

    for (int k0 = 0; k0 < 1024; k0 += 32) {
        uint4 av = *(const uint4*)&A[(m0 + sr) * 1024 + k0 + sk];
        uint4 bv = *(const uint4*)&B[(n0 + sr) * 1024 + k0 + sk];
        __syncthreads();
        *(uint4*)&As[sr][sk] = av;
        *(uint4*)&Bs[sr][sk] = bv;
        __syncthreads();
        short8 a0 = *(const short8*)&As[wm + fr][fk];
        short8 a1 = *(const short8*)&As[wm + 16 + fr][fk];
        short8 b0 = *(const short8*)&Bs[wn + fr][fk];
        short8 b1 = *(const short8*)&Bs[wn + 16 + fr][fk];
        acc[0][0] = __builtin_amdgcn_mfma_f32_16x16x32_bf16(a0, b0, acc[0][0], 0, 0, 0);
        acc[0][1] = __builtin_amdgcn_mfma_f32_16x16x32_bf16(a0, b1, acc[0][1], 0, 0, 0);
        acc[1][0] = __builtin_amdgcn_mfma_f32_16x16x32_bf16(a1, b0, acc[1][0], 0, 0, 0);
        acc[1][1] = __builtin_amdgcn_mfma_f32_16x16x32_bf16(a1, b1, acc[1][1], 0, 0, 0);
    }

    const int col = lane & 15;
    const int rq  = (lane >> 4) * 4;
    for (int mt = 0; mt < 2; mt++) {
        for (int nt = 0; nt < 2; nt++) {
            int gcol = n0 + wn + nt * 16 + col;
            float bv = bias[gcol];
            for (int r = 0; r < 4; r++) {
                int grow = m0 + wm + mt * 16 + rq + r;
                C[(size_t)grow * 4096 + gcol] = f32_to_bf16(acc[mt][nt][r] + bv);
            }
        }
    }
}

// ---------- phase 2: persistent recurrence, 64 blocks x 512 threads ----------
// Block bid owns hidden units j0=16*bid..+15 (64 gate rows = 4 gates x 16 units).
// W_hh slice lives ENTIRELY in VGPRs: af[gate][u] = 128 VGPRs/lane.
// __launch_bounds__(512,1): round-3's (512,2) capped VGPRs at 128 -> af was
// spilled/rematerialized every step (the mystery ~2.5 us/step). One block/CU is
// all we need (64 blocks, 256 CUs).
// DATAFLOW SYNC (no flags, no global barrier): each step t+1's h goes to a FRESH
// 64 KB slot hSeq[t+1] (512 slots = 32 MiB, overlays dead xA). Slots are
// pre-filled with 0xFFFFFFFF = (NaN,NaN) bf16 pair — IMPOSSIBLE as real h
// (|h|<1, sigmoid*tanh is never NaN). Consumers poll the exact dwordx4
// fragments they need until no word is sentinel: the data is its own flag.
// Removes producer drain->flag-store->flag-poll indirection AND the lockstep
// barrier: blocks run ahead dataflow-style; write-once slots -> no WAR hazard;
// per-dword check -> store tearing harmless; acyclic in t -> no deadlock.
// Raw sc1 LLC ops only — no compiler atomics (cache-maintenance storm, r3 note).
// NOTE (hipcc/gfx950 asm quirk): uint4 ok as "=v" OUTPUT, not "v" INPUT ->
// publish uses 2x dwordx2. Drain stays INSIDE publish asm (store-data reg reuse
// hazard). Rule #18: sched_barrier(0) after poll's vmcnt drain pins the
// register-only consumers (compares/MFMA) below it.
__global__ __launch_bounds__(512, 1) void lstm_persist(
    const float* __restrict__ Whh,          // [4096][1024] fp32
    const unsigned short* __restrict__ xg,  // bf16 [16384][4096], bias folded
    const float* __restrict__ c0,           // [32][1024] fp32
    unsigned int* __restrict__ hSeq,        // [512][16384] dwords, frag-order h
    float* __restrict__ out) {              // [32][1024] fp32
    __shared__ float partial[4][4][32][16];     // 32 KB [ks][gate][batch][unit]
    __shared__ unsigned short hout[32][16];     // 1 KB  [batch][unit]

    const int tid  = threadIdx.x;
    const int bid  = blockIdx.x;
    const int j0   = bid * 16;
    const int lane = tid & 63;
    const int wave = tid >> 6;
    const int ks   = wave >> 1;   // K-split 0..3 (256 k each)
    const int nt   = wave & 1;    // batch half (0-15 / 16-31)
    const int col  = lane & 15;
    const int quad = lane >> 4;

    // ---- stage W_hh slice -> A-fragments in VGPRs (once) ----
    // af[mt][u]: lane holds A[row = mt*16 + col][k-octet = (ks*8+u)*4 + quad].
    short8 af[4][8];
#pragma unroll
    for (int mt = 0; mt < 4; ++mt) {
#pragma unroll
        for (int u = 0; u < 8; ++u) {
            const float* wr = Whh + (size_t)(mt * 1024 + j0 + col) * 1024
                              + (ks * 8 + u) * 32 + quad * 8;
            float4 wa = *(const float4*)wr;
            float4 wb = *(const float4*)(wr + 4);
            short8 v;
            v[0] = (short)f32_to_bf16(wa.x); v[1] = (short)f32_to_bf16(wa.y);
            v[2] = (short)f32_to_bf16(wa.z); v[3] = (short)f32_to_bf16(wa.w);
            v[4] = (short)f32_to_bf16(wb.x); v[5] = (short)f32_to_bf16(wb.y);
            v[6] = (short)f32_to_bf16(wb.z); v[7] = (short)f32_to_bf16(wb.w);
            af[mt][u] = v;
        }
        asm volatile("" ::: "memory");  // cap transient staging register pressure
    }

    const int eb = tid >> 4;     // epilogue batch 0..31
    const int ej = tid & 15;     // epilogue unit  0..15
    float cst = c0[eb * 1024 + j0 + ej];

    const int kq0  = bid * 2;          // this block's two h k-octets
    const int bofs = nt * 16 + col;    // wave's batch index for B-frag / partial

    __syncthreads();

    for (int t = 0; t < 512; ++t) {
        const unsigned int* hR = hSeq + (size_t)t * 16384;
        unsigned int*       hW = hSeq + (size_t)(t + 1) * 16384;

        // prefetch xg gate inputs (independent of h, consumed in epilogue)
        const unsigned short* px = xg + (size_t)(eb * 512 + t) * 4096 + j0 + ej;
        unsigned short x0 = px[0];
        unsigned short x1 = px[1024];
        unsigned short x2 = px[2048];
        unsigned short x3 = px[3072];

        // poll-load B-fragments: sentinel 0xFFFFFFFF means "not yet written"
        uint4 bv[8];
        for (;;) {
#pragma unroll
            for (int u = 0; u < 8; ++u) {
                int kc = ks * 8 + u;
                const unsigned int* p = hR + ((kc * 4 + quad) * 32 + bofs) * 4;
                asm volatile("global_load_dwordx4 %0, %1, off sc1"
                             : "=v"(bv[u]) : "v"(p) : "memory");
            }
            asm volatile("s_waitcnt vmcnt(0)" ::: "memory");
            __builtin_amdgcn_sched_barrier(0);   // rule #18
            bool ok = true;
#pragma unroll
            for (int u = 0; u < 8; ++u)
                ok = ok && (bv[u].x != 0xFFFFFFFFu) && (bv[u].y != 0xFFFFFFFFu) &&
                           (bv[u].z != 0xFFFFFFFFu) && (bv[u].w != 0xFFFFFFFFu);
            if (__all(ok)) break;
            __builtin_amdgcn_s_sleep(1);
        }

        f32x4 acc[4] = {};
#pragma unroll
        for (int u = 0; u < 8; ++u) {
            union { uint4 u4; short8 s8; } cv;
            cv.u4 = bv[u];
#pragma unroll
            for (int mt = 0; mt < 4; ++mt)
                acc[mt] = __builtin_amdgcn_mfma_f32_16x16x32_bf16(af[mt][u], cv.s8,
                                                                  acc[mt], 0, 0, 0);
        }
        // write partials: C row (quad*4+r) = unit, C col = batch-local
#pragma unroll
        for (int mt = 0; mt < 4; ++mt)
            *(f32x4*)&partial[ks][mt][bofs][quad * 4] = acc[mt];
        __syncthreads();                      // (1) partials complete

        // epilogue: every thread owns one (batch, unit)
        float z[4];
#pragma unroll
        for (int q = 0; q < 4; ++q)
            z[q] = partial[0][q][eb][ej] + partial[1][q][eb][ej] +
                   partial[2][q][eb][ej] + partial[3][q][eb][ej];
        z[0] += bf16_to_f32(x0);
        z[1] += bf16_to_f32(x1);
        z[2] += bf16_to_f32(x2);
        z[3] += bf16_to_f32(x3);
        float ig = sigm_fast(z[0]);
        float fg = sigm_fast(z[1]);
        float gg = tanh_fast(z[2]);
        float og = sigm_fast(z[3]);
        cst = fg * cst + ig * gg;
        float hn = og * tanh_fast(cst);
        hout[eb][ej] = f32_to_bf16(hn);
        if (t == 511) {                       // uniform: final output, no publish
            out[eb * 1024 + j0 + ej] = hn;
            break;
        }
        __syncthreads();                      // (2) hout ready; partial reads done
                                              //     (gates next iter's partial writes)

        // publish this block's 16 h values per batch to the fresh slot.
        // drain INSIDE the asm: store-data regs must not be reused pre-retire.
        if (tid < 64) {
            int bb = tid & 31, kl = tid >> 5;
            uint2 d0 = *(const uint2*)&hout[bb][kl * 8];
            uint2 d1 = *(const uint2*)&hout[bb][kl * 8 + 4];
            unsigned int* p = hW + ((kq0 + kl) * 32 + bb) * 4;
            asm volatile("global_store_dwordx2 %0, %1, off sc1"
                         :: "v"(p), "v"(d0) : "memory");
            asm volatile("global_store_dwordx2 %0, %1, off sc1\n\ts_waitcnt vmcnt(0)"
                         :: "v"(p + 2), "v"(d1) : "memory");
        }
        // no barrier: waves run ahead; next-iter LDS writes are gated by (2)
    }
}

// ---------- launch ----------
extern "C" void kernel_launch(void* const* d_in, const int* in_sizes, int n_in,
                              void* d_out, int out_size, void* d_ws, size_t ws_size,
                              hipStream_t stream) {
    const float* x    = (const float*)d_in[0];  // [32][512][1024]
    const float* h0   = (const float*)d_in[1];  // [32][1024]
    const float* c0   = (const float*)d_in[2];  // [32][1024]
    const float* Wih  = (const float*)d_in[3];  // [4096][1024]
    const float* Whh  = (const float*)d_in[4];  // [4096][1024]
    const float* b_ih = (const float*)d_in[5];  // [4096]
    const float* b_hh = (const float*)d_in[6];  // [4096]
    float* out = (float*)d_out;
    char* ws = (char*)d_ws;

    // workspace layout (within the proven 176,439,296 B):
    //   xg    @ 0          134217728 B (bf16, live through persistent phase)
    //   xA    @ 134217728   33554432 B (bf16 x; DEAD after gemm -> hSeq overlay:
    //                                   512 slots x 65536 B = 33554432 B exactly)
    //   wB    @ 167772160    8388608 B (bf16 W_ih)
    //   bias  @ 176160768      16384 B
    unsigned short* xg   = (unsigned short*)(ws);
    unsigned short* xA   = (unsigned short*)(ws + 134217728);
    unsigned short* wB   = (unsigned short*)(ws + 167772160);
    float*          bias = (float*)(ws + 176160768);
    unsigned int*   hSeq = (unsigned int*)(ws + 134217728);  // overlays xA after gemm

    cvt_bf16_kernel<<<16384, 256, 0, stream>>>(x, xA, 16777216);
    cvt_bf16_kernel<<<4096, 256, 0, stream>>>(Wih, wB, 4194304);
    bias_add_kernel<<<16, 256, 0, stream>>>(b_ih, b_hh, bias);

    dim3 g1(64, 256);
    gemm_xproj<<<g1, 256, 0, stream>>>(xA, wB, bias, xg);

    // xA dead from here. Sentinel-fill slots 1..511 (slot 0 gets h0 next).
    fill_kernel<<<32704, 256, 0, stream>>>(hSeq + 16384, 0xFFFFFFFFu, 511 * 16384);
    hG_init_kernel<<<64, 256, 0, stream>>>(h0, hSeq);

    lstm_persist<<<64, 512, 0, stream>>>(Whh, xg, c0, hSeq, out);
}

// Round 7
// 1924.105 us; speedup vs baseline: 1.9371x; 1.0667x over previous
//
#include <hip/hip_runtime.h>
#include <stdint.h>

// ---------- types / helpers ----------
typedef __attribute__((ext_vector_type(8))) short short8;   // 8 bf16 in 4 VGPRs
typedef __attribute__((ext_vector_type(4))) float f32x4;

__device__ __forceinline__ unsigned short f32_to_bf16(float f) {
    unsigned int u = __float_as_uint(f);
    unsigned int r = (u + 0x7FFF + ((u >> 16) & 1)) >> 16;   // RNE
    return (unsigned short)r;
}
__device__ __forceinline__ float bf16_to_f32(unsigned short s) {
    return __uint_as_float(((unsigned int)s) << 16);
}

__device__ __forceinline__ float sigm_fast(float z) {
    return __fdividef(1.f, 1.f + __expf(-z));
}
__device__ __forceinline__ float tanh_fast(float z) {
    float a = fabsf(z);
    float e = __expf(-2.f * a);                 // in (0,1], no overflow
    float r = __fdividef(1.f - e, 1.f + e);
    return copysignf(r, z);
}

// ---------- prep kernels ----------
__global__ void cvt_bf16_kernel(const float* __restrict__ in,
                                unsigned short* __restrict__ out, int n) {
    int i = (blockIdx.x * blockDim.x + threadIdx.x) * 4;
    if (i >= n) return;
    float4 v = *(const float4*)(in + i);
    ushort4 o;
    o.x = f32_to_bf16(v.x);
    o.y = f32_to_bf16(v.y);
    o.z = f32_to_bf16(v.z);
    o.w = f32_to_bf16(v.w);
    *(ushort4*)(out + i) = o;
}

__global__ void bias_add_kernel(const float* __restrict__ bi,
                                const float* __restrict__ bh,
                                float* __restrict__ bias) {
    int i = blockIdx.x * blockDim.x + threadIdx.x;  // 4096
    bias[i] = bi[i] + bh[i];
}

__global__ void fill_kernel(unsigned int* __restrict__ p, unsigned int v, int n) {
    int i = blockIdx.x * blockDim.x + threadIdx.x;
    if (i < n) p[i] = v;
}

// h0 [b][j] fp32 -> slot 0 of hSeq in B-fragment order:
// dword D = ((kq)*32 + b)*4 + i2, holding bf16 h[j = kq*8 + i2*2], h[j+1] for batch b.
__global__ void hG_init_kernel(const float* __restrict__ h0,
                               unsigned int* __restrict__ hG) {
    int D = blockIdx.x * blockDim.x + threadIdx.x;  // 16384
    int i2 = D & 3, b = (D >> 2) & 31, kq = D >> 7;
    int j = kq * 8 + i2 * 2;
    unsigned int lo = f32_to_bf16(h0[b * 1024 + j]);
    unsigned int hi = f32_to_bf16(h0[b * 1024 + j + 1]);
    hG[D] = lo | (hi << 16);
}

// ---------- phase 1: xg[r][g] = bf16( x[r][:]·W_ih[g][:] + bias[g] ), r=b*512+t ----------
#define LDP 40  // padded LDS row pitch (shorts): 2-way conflicts only (free)

__global__ __launch_bounds__(256) void gemm_xproj(
    const unsigned short* __restrict__ A,   // x bf16 [16384][1024]
    const unsigned short* __restrict__ B,   // W_ih bf16 [4096][1024]
    const float* __restrict__ bias,         // [4096]
    unsigned short* __restrict__ C) {       // xg bf16 [16384][4096]
    __shared__ unsigned short As[64][LDP];
    __shared__ unsigned short Bs[64][LDP];
    const int tid  = threadIdx.x;
    const int lane = tid & 63;
    const int wave = tid >> 6;
    const int m0 = blockIdx.y * 64;
    const int n0 = blockIdx.x * 64;
    const int wm = (wave & 1) * 32;
    const int wn = (wave >> 1) * 32;

    f32x4 acc[2][2] = {};

    const int sr = tid >> 2;
    const int sk = (tid & 3) * 8;
    const int fr = lane & 15;
    const int fk = (lane >> 4) * 8;

    for (int k0 = 0; k0 < 1024; k0 += 32) {
        uint4 av = *(const uint4*)&A[(m0 + sr) * 1024 + k0 + sk];
        uint4 bv = *(const uint4*)&B[(n0 + sr) * 1024 + k0 + sk];
        __syncthreads();
        *(uint4*)&As[sr][sk] = av;
        *(uint4*)&Bs[sr][sk] = bv;
        __syncthreads();
        short8 a0 = *(const short8*)&As[wm + fr][fk];
        short8 a1 = *(const short8*)&As[wm + 16 + fr][fk];
        short8 b0 = *(const short8*)&Bs[wn + fr][fk];
        short8 b1 = *(const short8*)&Bs[wn + 16 + fr][fk];
        acc[0][0] = __builtin_amdgcn_mfma_f32_16x16x32_bf16(a0, b0, acc[0][0], 0, 0, 0);
        acc[0][1] = __builtin_amdgcn_mfma_f32_16x16x32_bf16(a0, b1, acc[0][1], 0, 0, 0);
        acc[1][0] = __builtin_amdgcn_mfma_f32_16x16x32_bf16(a1, b0, acc[1][0], 0, 0, 0);
        acc[1][1] = __builtin_amdgcn_mfma_f32_16x16x32_bf16(a1, b1, acc[1][1], 0, 0, 0);
    }

    const int col = lane & 15;
    const int rq  = (lane >> 4) * 4;
    for (int mt = 0; mt < 2; mt++) {
        for (int nt = 0; nt < 2; nt++) {
            int gcol = n0 + wn + nt * 16 + col;
            float bv = bias[gcol];
            for (int r = 0; r < 4; r++) {
                int grow = m0 + wm + mt * 16 + rq + r;
                C[(size_t)grow * 4096 + gcol] = f32_to_bf16(acc[mt][nt][r] + bv);
            }
        }
    }
}

// ---------- phase 2: persistent recurrence, 64 blocks x 512 threads ----------
// Round-4-proven dataflow core (fresh sentinel-filled slot per step; data is its
// own flag; poll drains vmcnt(0) EVERY retry so no load-dest register is ever
// reused while in flight — the round-5 pipelined poll violated that and caused
// GPU memory faults via clobbered address registers). Deltas vs round 4:
//  * ONE barrier/step: partial[] double-buffered by step parity (the t+2 write
//    is ordered behind the t read transitively through the t+1 barrier).
//  * h published straight from epilogue registers: shfl_xor pair-pack, even-ej
//    lanes store one dword (vmcnt(0) INSIDE the asm for store-reg lifetime).
//    Removes the hout LDS round-trip and the second __syncthreads.
//  * partial unit-dim padded 16->20 floats: 80 B rows keep 16 B alignment for
//    ds_write_b128; write-side bank conflicts 8-way -> 4-way (r4: 2.5e7 cyc).
// Rule #18: sched_barrier(0) after the poll's vmcnt drain pins the
// register-only MFMA/compare consumers below it.
__global__ __launch_bounds__(512, 1) void lstm_persist(
    const float* __restrict__ Whh,          // [4096][1024] fp32
    const unsigned short* __restrict__ xg,  // bf16 [16384][4096], bias folded
    const float* __restrict__ c0,           // [32][1024] fp32
    unsigned int* __restrict__ hSeq,        // [512][16384] dwords, frag-order h
    float* __restrict__ out) {              // [32][1024] fp32
    __shared__ float partial[2][4][4][32][20];   // 80 KB [par][ks][gate][batch][unit pad20]

    const int tid  = threadIdx.x;
    const int bid  = blockIdx.x;
    const int j0   = bid * 16;
    const int lane = tid & 63;
    const int wave = tid >> 6;
    const int ks   = wave >> 1;   // K-split 0..3 (256 k each)
    const int nt   = wave & 1;    // batch half (0-15 / 16-31)
    const int col  = lane & 15;
    const int quad = lane >> 4;

    // ---- stage W_hh slice -> A-fragments in VGPRs/AGPRs (once) ----
    // af[mt][u]: lane holds A[row = mt*16 + col][k-octet = (ks*8+u)*4 + quad].
    short8 af[4][8];
#pragma unroll
    for (int mt = 0; mt < 4; ++mt) {
#pragma unroll
        for (int u = 0; u < 8; ++u) {
            const float* wr = Whh + (size_t)(mt * 1024 + j0 + col) * 1024
                              + (ks * 8 + u) * 32 + quad * 8;
            float4 wa = *(const float4*)wr;
            float4 wb = *(const float4*)(wr + 4);
            short8 v;
            v[0] = (short)f32_to_bf16(wa.x); v[1] = (short)f32_to_bf16(wa.y);
            v[2] = (short)f32_to_bf16(wa.z); v[3] = (short)f32_to_bf16(wa.w);
            v[4] = (short)f32_to_bf16(wb.x); v[5] = (short)f32_to_bf16(wb.y);
            v[6] = (short)f32_to_bf16(wb.z); v[7] = (short)f32_to_bf16(wb.w);
            af[mt][u] = v;
        }
        asm volatile("" ::: "memory");  // cap transient staging register pressure
    }

    const int eb = tid >> 4;     // epilogue batch 0..31
    const int ej = tid & 15;     // epilogue unit  0..15
    float cst = c0[eb * 1024 + j0 + ej];

    const int kq0  = bid * 2;          // this block's two h k-octets
    const int bofs = nt * 16 + col;    // wave's batch index for B-frag / partial
    // publish dword offset within a slot (t-invariant); even-ej lanes store.
    const int poff = ((kq0 + (ej >> 3)) * 32 + eb) * 4 + ((ej & 7) >> 1);

    __syncthreads();

    for (int t = 0; t < 512; ++t) {
        const unsigned int* hR = hSeq + ((size_t)t << 14);

        // prefetch xg gate inputs (independent of h, consumed in epilogue;
        // plain loads -> compiler manages waitcnt; issued before poll/MFMA)
        const unsigned short* px = xg + (size_t)(eb * 512 + t) * 4096 + j0 + ej;
        unsigned short x0 = px[0];
        unsigned short x1 = px[1024];
        unsigned short x2 = px[2048];
        unsigned short x3 = px[3072];

        // poll-load B-fragments: sentinel 0xFFFFFFFF means "not yet written".
        // Drain-to-zero every retry: no load-dest register is ever reused while
        // a load is in flight (the r5 crash mechanism).
        uint4 bv[8];
        for (;;) {
#pragma unroll
            for (int u = 0; u < 8; ++u) {
                int kc = ks * 8 + u;
                const unsigned int* p = hR + ((kc * 4 + quad) * 32 + bofs) * 4;
                asm volatile("global_load_dwordx4 %0, %1, off sc1"
                             : "=v"(bv[u]) : "v"(p) : "memory");
            }
            asm volatile("s_waitcnt vmcnt(0)" ::: "memory");
            __builtin_amdgcn_sched_barrier(0);   // rule #18
            bool ok = true;
#pragma unroll
            for (int u = 0; u < 8; ++u)
                ok = ok && (bv[u].x != 0xFFFFFFFFu) && (bv[u].y != 0xFFFFFFFFu) &&
                           (bv[u].z != 0xFFFFFFFFu) && (bv[u].w != 0xFFFFFFFFu);
            if (__all(ok)) break;
            __builtin_amdgcn_s_sleep(1);
        }

        f32x4 acc[4] = {};
#pragma unroll
        for (int u = 0; u < 8; ++u) {
            union { uint4 u4; short8 s8; } cv;
            cv.u4 = bv[u];
#pragma unroll
            for (int mt = 0; mt < 4; ++mt)
                acc[mt] = __builtin_amdgcn_mfma_f32_16x16x32_bf16(af[mt][u], cv.s8,
                                                                  acc[mt], 0, 0, 0);
        }
        // write partials: C row (quad*4+r) = unit, C col = batch-local
        const int p = t & 1;
#pragma unroll
        for (int mt = 0; mt < 4; ++mt)
            *(f32x4*)&partial[p][ks][mt][bofs][quad * 4] = acc[mt];
        __syncthreads();                          // the ONE barrier per step

        // epilogue: every thread owns one (batch, unit)
        float z[4];
#pragma unroll
        for (int q = 0; q < 4; ++q)
            z[q] = partial[p][0][q][eb][ej] + partial[p][1][q][eb][ej] +
                   partial[p][2][q][eb][ej] + partial[p][3][q][eb][ej];
        z[0] += bf16_to_f32(x0);
        z[1] += bf16_to_f32(x1);
        z[2] += bf16_to_f32(x2);
        z[3] += bf16_to_f32(x3);
        float ig = sigm_fast(z[0]);
        float fg = sigm_fast(z[1]);
        float gg = tanh_fast(z[2]);
        float og = sigm_fast(z[3]);
        cst = fg * cst + ig * gg;
        float hn = og * tanh_fast(cst);
        if (t == 511) {                           // uniform: final output, no publish
            out[eb * 1024 + j0 + ej] = hn;
            break;
        }

        // publish straight from registers: pair-pack via shfl, even-ej lanes
        // store one dword. vmcnt(0) INSIDE the asm (store-reg lifetime safety);
        // it overlaps the propagation delay all consumers wait out anyway.
        float hp = __shfl_xor(hn, 1);
        unsigned lo16 = f32_to_bf16(hn), hi16 = f32_to_bf16(hp);
        unsigned pack = lo16 | (hi16 << 16);
        unsigned int* pw = hSeq + ((size_t)(t + 1) << 14) + poff;
        if ((ej & 1) == 0) {
            asm volatile("global_store_dword %0, %1, off sc1\n\ts_waitcnt vmcnt(0)"
                         :: "v"(pw), "v"(pack) : "memory");
        }
        // no second barrier: next iter writes partial[p^1]; the t+1 barrier
        // transitively orders the t+2 write behind this iter's reads.
    }
}

// ---------- launch ----------
extern "C" void kernel_launch(void* const* d_in, const int* in_sizes, int n_in,
                              void* d_out, int out_size, void* d_ws, size_t ws_size,
                              hipStream_t stream) {
    const float* x    = (const float*)d_in[0];  // [32][512][1024]
    const float* h0   = (const float*)d_in[1];  // [32][1024]
    const float* c0   = (const float*)d_in[2];  // [32][1024]
    const float* Wih  = (const float*)d_in[3];  // [4096][1024]
    const float* Whh  = (const float*)d_in[4];  // [4096][1024]
    const float* b_ih = (const float*)d_in[5];  // [4096]
    const float* b_hh = (const float*)d_in[6];  // [4096]
    float* out = (float*)d_out;
    char* ws = (char*)d_ws;

    // workspace layout (within the proven 176,439,296 B):
    //   xg    @ 0          134217728 B (bf16, live through persistent phase)
    //   xA    @ 134217728   33554432 B (bf16 x; DEAD after gemm -> hSeq overlay:
    //                                   512 slots x 65536 B = 33554432 B exactly)
    //   wB    @ 167772160    8388608 B (bf16 W_ih)
    //   bias  @ 176160768      16384 B
    unsigned short* xg   = (unsigned short*)(ws);
    unsigned short* xA   = (unsigned short*)(ws + 134217728);
    unsigned short* wB   = (unsigned short*)(ws + 167772160);
    float*          bias = (float*)(ws + 176160768);
    unsigned int*   hSeq = (unsigned int*)(ws + 134217728);  // overlays xA after gemm

    cvt_bf16_kernel<<<16384, 256, 0, stream>>>(x, xA, 16777216);
    cvt_bf16_kernel<<<4096, 256, 0, stream>>>(Wih, wB, 4194304);
    bias_add_kernel<<<16, 256, 0, stream>>>(b_ih, b_hh, bias);

    dim3 g1(64, 256);
    gemm_xproj<<<g1, 256, 0, stream>>>(xA, wB, bias, xg);

    // xA dead from here. Sentinel-fill slots 1..511 (slot 0 gets h0 next).
    fill_kernel<<<32704, 256, 0, stream>>>(hSeq + 16384, 0xFFFFFFFFu, 511 * 16384);
    hG_init_kernel<<<64, 256, 0, stream>>>(h0, hSeq);

    lstm_persist<<<64, 512, 0, stream>>>(Whh, xg, c0, hSeq, out);
}